// Round 16
// baseline (471.385 us; speedup 1.0000x reference)
//
#include <hip/hip_runtime.h>
#include <math.h>

#define NTOK 131072
#define EMB  2048
#define UDIM 128
#define KDIM 2176   // EMB + UDIM
#define NE   64
#define TOPK 8

#define BM     128   // tokens per block (4 waves x 32 tokens)
#define NSUB   34    // 64-K sub-chunks (2 MFMA ks-steps each)
#define NCHK   17    // 128-K X chunks
#define NKSTEP 68
#define LSTR   65    // f32 logits row stride in LDS
#define MARGIN 1e-4f // rank-8/9 gap below which we recompute in f64
#define WPLANE ((size_t)NKSTEP * 64 * 32)   // bf16 elems per W plane

typedef short bf16x8 __attribute__((ext_vector_type(8)));
typedef float f32x4  __attribute__((ext_vector_type(4)));

union FragU { uint4 u; bf16x8 v; };

__device__ __forceinline__ unsigned rnbf(unsigned u) {
    return u + 0x7FFFu + ((u >> 16) & 1u);   // RNE f32->bf16 (top 16 bits)
}

__device__ __forceinline__ void cvt8(const float4 a, const float4 b,
                                     uint4& hi, uint4& lo) {
    const float x[8] = {a.x, a.y, a.z, a.w, b.x, b.y, b.z, b.w};
    unsigned hh[4], ll[4];
    #pragma unroll
    for (int p = 0; p < 4; ++p) {
        const unsigned u0 = __float_as_uint(x[2*p]);
        const unsigned u1 = __float_as_uint(x[2*p+1]);
        const unsigned r0 = rnbf(u0), r1 = rnbf(u1);
        hh[p] = (r0 >> 16) | (r1 & 0xFFFF0000u);
        const float h0 = __uint_as_float(r0 & 0xFFFF0000u);
        const float h1 = __uint_as_float(r1 & 0xFFFF0000u);
        const unsigned s0 = rnbf(__float_as_uint(x[2*p]   - h0));
        const unsigned s1 = rnbf(__float_as_uint(x[2*p+1] - h1));
        ll[p] = (s0 >> 16) | (s1 & 0xFFFF0000u);
    }
    hi = make_uint4(hh[0], hh[1], hh[2], hh[3]);
    lo = make_uint4(ll[0], ll[1], ll[2], ll[3]);
}

// direct-to-LDS 16B async copy: per-lane global src, wave-uniform LDS dst
__device__ __forceinline__ void gll16(const void* gsrc, void* ldst) {
    __builtin_amdgcn_global_load_lds(
        (const __attribute__((address_space(1))) void*)gsrc,
        (__attribute__((address_space(3))) void*)ldst, 16, 0, 0);
}

// W f32 -> bf16 hi/lo planes, LANE-LINEAR per-ks order (round-11 layout)
__global__ __launch_bounds__(256)
void prep_w(const float* __restrict__ W,
            unsigned short* __restrict__ wh,
            unsigned short* __restrict__ wl)
{
    const int t = blockIdx.x * 256 + threadIdx.x;
    if (t >= NKSTEP * 64 * 4) return;
    const int lk = t & 3, e = (t >> 2) & 63, ks = t >> 8;
    const float* p = W + (size_t)e * KDIM + ks * 32 + lk * 8;
    const float4 a = *reinterpret_cast<const float4*>(p);
    const float4 c = *reinterpret_cast<const float4*>(p + 4);
    uint4 hi, lo;
    cvt8(a, c, hi, lo);
    const size_t di = (size_t)ks * 2048 +
                      ((size_t)((e >> 4) * 64 + (e & 15) + 16 * lk)) * 8;
    *reinterpret_cast<uint4*>(wh + di) = hi;
    *reinterpret_cast<uint4*>(wl + di) = lo;
}

__global__ void zero_flags(int* flagbuf) {
    if (threadIdx.x == 0 && blockIdx.x == 0) flagbuf[0] = 0;
}

__global__ __launch_bounds__(256, 3)
void gate_main(const float* __restrict__ h,
               const float* __restrict__ u,
               const unsigned short* __restrict__ wh,
               const unsigned short* __restrict__ wl,
               const float* __restrict__ b,
               int* __restrict__ flagbuf,
               float* __restrict__ out)
{
    // smem: K loop = W TRIPLE buffer (3 x 16KB: [hi 8KB | lo 8KB] per 64-K
    // sub-chunk); after final barrier = f32 logits [128][65] (33280 B, aliased).
    __shared__ __align__(16) char smem[49152];
    __shared__ int flaglist[BM];
    __shared__ int nflag;

    const int tid  = threadIdx.x;
    const int lane = tid & 63;
    const int wid  = tid >> 6;
    const int bm   = blockIdx.x * BM;
    const int lrow = lane & 15;
    const int lk   = lane >> 4;

    if (tid == 0) nflag = 0;

    f32x4 acc[2][4];
    #pragma unroll
    for (int mi = 0; mi < 2; ++mi)
        #pragma unroll
        for (int ni = 0; ni < 4; ++ni)
            acc[mi][ni] = (f32x4){0.f, 0.f, 0.f, 0.f};

    float4 xr[16];   // one 128-K chunk: [mi][s:0..3][d:0..1], refilled by halves

    // stage 64-K group g's W (16KB) into LDS ring buffer rb (4 glls/wave)
    auto stageW = [&](int g, int rb) {
        const char* hsrc = (const char*)wh + (size_t)g * 8192;
        const char* lsrc = (const char*)wl + (size_t)g * 8192;
        char* dst = smem + rb * 16384;
        #pragma unroll
        for (int i = 0; i < 2; ++i) {
            const int o = wid * 2048 + i * 1024;
            gll16(hsrc + o + lane * 16, dst + o);
            gll16(lsrc + o + lane * 16, dst + 8192 + o);
        }
    };

// refill half H (0=K[0,64), 1=K[64,128)) of chunk C into xr (8 loads, 8KB/wave)
#define LOADX_HALF(C, H) do {                                                   \
    const int c_ = (C);                                                         \
    const bool fh_ = (c_ < 16);                                                 \
    const float* src_ = fh_ ? h : u;                                            \
    const int ld_ = fh_ ? EMB : UDIM;                                           \
    const int kb_ = c_ * 128 - (fh_ ? 0 : EMB) + (H) * 64;                      \
    _Pragma("unroll")                                                           \
    for (int mi = 0; mi < 2; ++mi) {                                            \
        const size_t ro_ = (size_t)(bm + wid*32 + mi*16 + lrow) * ld_ + kb_ + lk*8; \
        xr[mi*8 + (H)*4 + 0] = *reinterpret_cast<const float4*>(src_ + ro_);      \
        xr[mi*8 + (H)*4 + 1] = *reinterpret_cast<const float4*>(src_ + ro_ + 4);  \
        xr[mi*8 + (H)*4 + 2] = *reinterpret_cast<const float4*>(src_ + ro_ + 32); \
        xr[mi*8 + (H)*4 + 3] = *reinterpret_cast<const float4*>(src_ + ro_ + 36); \
    }                                                                           \
} while (0)

// sub-chunk compute: P = half (0/1), T = chunk; consumes xr half P, then
// refills it for chunk T+1 (if REFILL). All xr indices compile-time.
#define COMPUTE_SUB(P, T, REFILL) do {                                          \
    const uint4* wb_ = reinterpret_cast<const uint4*>(                          \
        smem + ((2*(T) + (P)) % 3) * 16384);                                    \
    _Pragma("unroll")                                                           \
    for (int sl = 0; sl < 2; ++sl) {                                            \
        FragU bh_[4], bl_[4];                                                   \
        _Pragma("unroll")                                                       \
        for (int ni = 0; ni < 4; ++ni) {                                        \
            bh_[ni].u = wb_[sl*256 + ni*64 + lane];                             \
            bl_[ni].u = wb_[512 + sl*256 + ni*64 + lane];                       \
        }                                                                       \
        FragU ah0_, al0_, ah1_, al1_;                                           \
        cvt8(xr[((P)*2+sl)*2 + 0], xr[((P)*2+sl)*2 + 1], ah0_.u, al0_.u);       \
        cvt8(xr[8 + ((P)*2+sl)*2 + 0], xr[8 + ((P)*2+sl)*2 + 1], ah1_.u, al1_.u); \
        if (sl == 1 && (REFILL)) { LOADX_HALF((T) + 1, P); }                    \
        _Pragma("unroll")                                                       \
        for (int ni = 0; ni < 4; ++ni) {                                        \
            acc[0][ni] = __builtin_amdgcn_mfma_f32_16x16x32_bf16(ah0_.v, bh_[ni].v, acc[0][ni], 0,0,0); \
            acc[0][ni] = __builtin_amdgcn_mfma_f32_16x16x32_bf16(ah0_.v, bl_[ni].v, acc[0][ni], 0,0,0); \
            acc[0][ni] = __builtin_amdgcn_mfma_f32_16x16x32_bf16(al0_.v, bh_[ni].v, acc[0][ni], 0,0,0); \
            acc[1][ni] = __builtin_amdgcn_mfma_f32_16x16x32_bf16(ah1_.v, bh_[ni].v, acc[1][ni], 0,0,0); \
            acc[1][ni] = __builtin_amdgcn_mfma_f32_16x16x32_bf16(ah1_.v, bl_[ni].v, acc[1][ni], 0,0,0); \
            acc[1][ni] = __builtin_amdgcn_mfma_f32_16x16x32_bf16(al1_.v, bh_[ni].v, acc[1][ni], 0,0,0); \
        }                                                                       \
    }                                                                           \
} while (0)

#define SB0 __builtin_amdgcn_sched_barrier(0)
// counted barrier: stage glls needed next sub-chunk are OLDER than the 20
// youngest (2 x 8-load X refills + 4-gll next stage) -> they complete, X rides.
#define BAR20 do { SB0; asm volatile("s_waitcnt vmcnt(20)" ::: "memory"); \
                   __builtin_amdgcn_s_barrier(); SB0; } while (0)

    // ---- prologue: W(0),W(1) staged; chunk 0 fully in flight ----
    stageW(0, 0);
    stageW(1, 1);
    SB0;
    LOADX_HALF(0, 0);
    LOADX_HALF(0, 1);
    BAR20;   // ensures stage(0) done (20 younger: stage(1)+16 X loads)

    // ---- main loop: chunks 0..15, uniform vmcnt(20) barriers ----
    #pragma unroll 1
    for (int t = 0; t < 16; ++t) {
        stageW(2*t + 2, (2*t + 2) % 3);
        SB0;
        COMPUTE_SUB(0, t, 1);
        BAR20;                       // needs stage(2t+1): 20 younger entries
        stageW(2*t + 3, (2*t + 3) % 3);
        SB0;
        COMPUTE_SUB(1, t, 1);
        BAR20;                       // needs stage(2t+2): 20 younger entries
    }
    // ---- peeled t=16: no more staging/refills ----
    COMPUTE_SUB(0, 16, 0);
    SB0;
    asm volatile("s_waitcnt vmcnt(8)" ::: "memory");  // stage(33) done; keep 8
    __builtin_amdgcn_s_barrier();
    SB0;
    COMPUTE_SUB(1, 16, 0);
    __syncthreads();   // full drain before LDS re-alias

#undef COMPUTE_SUB
#undef LOADX_HALF
#undef BAR20
#undef SB0

    // ---- C-write: logits + bias into f32 LDS (aliases W ring) ----
    float* ls = reinterpret_cast<float*>(smem);
    #pragma unroll
    for (int mi = 0; mi < 2; ++mi)
        #pragma unroll
        for (int ni = 0; ni < 4; ++ni) {
            const float be = b[ni*16 + lrow];
            #pragma unroll
            for (int r = 0; r < 4; ++r) {
                const int tl = wid*32 + mi*16 + lk*4 + r;
                const int e  = ni*16 + lrow;
                ls[tl * LSTR + e] = acc[mi][ni][r] + be;
            }
        }
    __syncthreads();

    // ---- per-token top-8 + margin + softmax (1 thread : 1 token) ----
    if (tid < BM) {
        float* row = ls + tid * LSTR;
        unsigned long long selm = 0ULL;
        float mx = 0.f, l8 = 0.f, l9 = 0.f;
        for (int s = 0; s < TOPK + 1; ++s) {
            float best = -1e30f; int bi = 0;
            #pragma unroll
            for (int e = 0; e < NE; ++e) {
                const float v = row[e];
                if (!((selm >> e) & 1ULL) && v > best) { best = v; bi = e; }
            }
            if (s == 0) mx = best;
            if (s < TOPK) selm |= 1ULL << bi;
            if (s == TOPK - 1) l8 = best;
            if (s == TOPK)     l9 = best;
        }
        if (l8 - l9 < MARGIN) {
            const int slot = atomicAdd(&nflag, 1);
            flaglist[slot] = tid;
        }
        float tot = 0.f, s8 = 0.f;
        #pragma unroll
        for (int e = 0; e < NE; ++e) {
            const float p = __expf(row[e] - mx);
            tot += p;
            if ((selm >> e) & 1ULL) s8 += p;
            row[e] = p;
        }
        const float inv = 1.f / (s8 + 1e-9f * tot);
        #pragma unroll
        for (int e = 0; e < NE; ++e)
            row[e] = ((selm >> e) & 1ULL) ? row[e] * inv : 0.f;
    }
    __syncthreads();

    // ---- coalesced float4 store ----
    {
        const int tx = tid & 15, ty = tid >> 4;
        #pragma unroll
        for (int r = 0; r < 8; ++r) {
            const int m = ty + r * 16;
            float4 v;
            v.x = ls[m * LSTR + tx*4 + 0];
            v.y = ls[m * LSTR + tx*4 + 1];
            v.z = ls[m * LSTR + tx*4 + 2];
            v.w = ls[m * LSTR + tx*4 + 3];
            *reinterpret_cast<float4*>(out + (size_t)(bm + m) * NE + tx*4) = v;
        }
    }

    // ---- publish flagged tokens (device-scope atomics) ----
    if (tid < nflag) {
        const int slot = atomicAdd(flagbuf, 1);
        flagbuf[1 + slot] = bm + flaglist[tid];
    }
}

// ---- exact f64 referee for margin-flagged tokens (reads original f32 W) ----
__global__ __launch_bounds__(256)
void gate_refine(const float* __restrict__ h,
                 const float* __restrict__ u,
                 const float* __restrict__ W,
                 const float* __restrict__ b,
                 const int* __restrict__ flagbuf,
                 float* __restrict__ out)
{
    __shared__ double dscr[576];
    const int nf = flagbuf[0];
    for (int f = blockIdx.x; f < nf; f += gridDim.x) {
        const int tok  = flagbuf[1 + f];
        const int tid  = threadIdx.x;
        const int e    = tid & 63;
        const int part = tid >> 6;
        const int ka = part * 544, kb2 = ka + 544;
        double s = 0.0;
        #pragma unroll 4
        for (int k = ka; k < kb2; ++k) {
            const float xv = (k < EMB) ? h[(size_t)tok * EMB + k]
                                       : u[(size_t)tok * UDIM + (k - EMB)];
            s = fma((double)xv, (double)W[(size_t)e * KDIM + k], s);
        }
        dscr[part * 64 + e] = s;
        __syncthreads();
        if (tid < NE) {
            const double l = dscr[tid] + dscr[64 + tid] + dscr[128 + tid] +
                             dscr[192 + tid] + (double)b[tid];
            dscr[512 + tid] = l;
        }
        __syncthreads();
        if (tid == 0) {
            double* dl = dscr + 512;
            double mx = dl[0];
            #pragma unroll
            for (int e2 = 1; e2 < NE; ++e2) mx = fmax(mx, dl[e2]);
            double tot = 0.0;
            #pragma unroll
            for (int e2 = 0; e2 < NE; ++e2) {
                const double p = exp(dl[e2] - mx);
                dl[e2] = p;
                tot += p;
            }
            double s8 = 0.0;
            for (int ss = 0; ss < TOPK; ++ss) {
                double best = -1.0; int bi = 0;
                for (int e2 = 0; e2 < NE; ++e2) {
                    const double p = dl[e2];
                    if (p > best) { best = p; bi = e2; }
                }
                s8 += best;
                dl[bi] = -best;
            }
            const double inv = 1.0 / (s8 + 1e-9 * tot);
            for (int e2 = 0; e2 < NE; ++e2) {
                const double p = dl[e2];
                out[(size_t)tok * NE + e2] = (float)((p < 0.0) ? (-p) * inv : 0.0);
            }
        }
        __syncthreads();
    }
}

extern "C" void kernel_launch(void* const* d_in, const int* in_sizes, int n_in,
                              void* d_out, int out_size, void* d_ws, size_t ws_size,
                              hipStream_t stream) {
    const float* h = (const float*)d_in[0];
    const float* u = (const float*)d_in[1];
    const float* W = (const float*)d_in[2];
    const float* b = (const float*)d_in[3];
    float* out = (float*)d_out;
    (void)in_sizes; (void)n_in; (void)out_size; (void)ws_size;

    unsigned short* wh = (unsigned short*)d_ws;
    unsigned short* wl = wh + WPLANE;
    int* flagbuf = (int*)(wl + WPLANE);

    hipLaunchKernelGGL(zero_flags, dim3(1), dim3(64), 0, stream, flagbuf);
    hipLaunchKernelGGL(prep_w, dim3(NKSTEP), dim3(256), 0, stream, W, wh, wl);
    hipLaunchKernelGGL(gate_main, dim3(NTOK / BM), dim3(256), 0, stream,
                       h, u, wh, wl, b, flagbuf, out);
    hipLaunchKernelGGL(gate_refine, dim3(256), dim3(256), 0, stream,
                       h, u, W, b, flagbuf, out);
}

// Round 17
// 391.505 us; speedup vs baseline: 1.2040x; 1.2040x over previous
//
#include <hip/hip_runtime.h>
#include <math.h>

#define NTOK 131072
#define EMB  2048
#define UDIM 128
#define KDIM 2176   // EMB + UDIM
#define NE   64
#define TOPK 8

#define BM     128   // tokens per block (4 waves x 32 tokens)
#define BK     64    // K chunk (2 MFMA K-steps)
#define NCHUNK 34    // KDIM / BK
#define NKSTEP 68    // KDIM / 32
#define LSTR   65    // f32 logits row stride in LDS
#define MARGIN 1e-4f // rank-8/9 gap below which we recompute in f64
#define WPLANE ((size_t)NKSTEP * 64 * 32)   // bf16 elems per W plane

typedef short bf16x8 __attribute__((ext_vector_type(8)));
typedef float f32x4  __attribute__((ext_vector_type(4)));

union FragU { uint4 u; bf16x8 v; };

__device__ __forceinline__ unsigned rnbf(unsigned u) {
    return u + 0x7FFFu + ((u >> 16) & 1u);   // RNE f32->bf16 (top 16 bits)
}

__device__ __forceinline__ void cvt8(const float4 a, const float4 b,
                                     uint4& hi, uint4& lo) {
    const float x[8] = {a.x, a.y, a.z, a.w, b.x, b.y, b.z, b.w};
    unsigned hh[4], ll[4];
    #pragma unroll
    for (int p = 0; p < 4; ++p) {
        const unsigned u0 = __float_as_uint(x[2*p]);
        const unsigned u1 = __float_as_uint(x[2*p+1]);
        const unsigned r0 = rnbf(u0), r1 = rnbf(u1);
        hh[p] = (r0 >> 16) | (r1 & 0xFFFF0000u);
        const float h0 = __uint_as_float(r0 & 0xFFFF0000u);
        const float h1 = __uint_as_float(r1 & 0xFFFF0000u);
        const unsigned s0 = rnbf(__float_as_uint(x[2*p]   - h0));
        const unsigned s1 = rnbf(__float_as_uint(x[2*p+1] - h1));
        ll[p] = (s0 >> 16) | (s1 & 0xFFFF0000u);
    }
    hi = make_uint4(hh[0], hh[1], hh[2], hh[3]);
    lo = make_uint4(ll[0], ll[1], ll[2], ll[3]);
}

// direct-to-LDS 16B async copy: per-lane global src, wave-uniform LDS dst
__device__ __forceinline__ void gll16(const void* gsrc, void* ldst) {
    __builtin_amdgcn_global_load_lds(
        (const __attribute__((address_space(1))) void*)gsrc,
        (__attribute__((address_space(3))) void*)ldst, 16, 0, 0);
}

// W f32 -> bf16 hi/lo planes, LANE-LINEAR per-ks order; also zeroes flag count.
__global__ __launch_bounds__(256)
void prep_w(const float* __restrict__ W,
            unsigned short* __restrict__ wh,
            unsigned short* __restrict__ wl,
            int* __restrict__ flagbuf)
{
    const int t = blockIdx.x * 256 + threadIdx.x;
    if (t == 0) flagbuf[0] = 0;
    if (t >= NKSTEP * 64 * 4) return;
    const int lk = t & 3, e = (t >> 2) & 63, ks = t >> 8;
    const float* p = W + (size_t)e * KDIM + ks * 32 + lk * 8;
    const float4 a = *reinterpret_cast<const float4*>(p);
    const float4 c = *reinterpret_cast<const float4*>(p + 4);
    uint4 hi, lo;
    cvt8(a, c, hi, lo);
    const size_t di = (size_t)ks * 2048 +
                      ((size_t)((e >> 4) * 64 + (e & 15) + 16 * lk)) * 8;
    *reinterpret_cast<uint4*>(wh + di) = hi;
    *reinterpret_cast<uint4*>(wl + di) = lo;
}

__global__ __launch_bounds__(256, 4)
void gate_main(const float* __restrict__ h,
               const float* __restrict__ u,
               const unsigned short* __restrict__ wh,
               const unsigned short* __restrict__ wl,
               const float* __restrict__ b,
               int* __restrict__ flagbuf,
               float* __restrict__ out)
{
    // smem: during K loop = W double buffer (2 x 16KB: [hi 8KB | lo 8KB]);
    // after final barrier = f32 logits [128][65]. 33536 B total.
    __shared__ __align__(16) char smem[33536];

    const int tid  = threadIdx.x;
    const int lane = tid & 63;
    const int wid  = tid >> 6;
    const int bm   = blockIdx.x * BM;
    const int lrow = lane & 15;
    const int lk   = lane >> 4;

    f32x4 acc[2][4];
    #pragma unroll
    for (int mi = 0; mi < 2; ++mi)
        #pragma unroll
        for (int ni = 0; ni < 4; ++ni)
            acc[mi][ni] = (f32x4){0.f, 0.f, 0.f, 0.f};

    float4 xr[8];

    auto loadX = [&](int c) {
        const bool  fh  = (c < 32);
        const float* src = fh ? h : u;
        const int   ld  = fh ? EMB : UDIM;
        const int   kb  = c * BK - (fh ? 0 : EMB);
        #pragma unroll
        for (int mi = 0; mi < 2; ++mi) {
            const size_t ro = (size_t)(bm + wid*32 + mi*16 + lrow) * ld + kb + lk*8;
            #pragma unroll
            for (int s = 0; s < 2; ++s) {
                xr[mi*4 + s*2 + 0] = *reinterpret_cast<const float4*>(src + ro + s*32);
                xr[mi*4 + s*2 + 1] = *reinterpret_cast<const float4*>(src + ro + s*32 + 4);
            }
        }
    };

    // stage chunk c's W (16KB: hi 8KB + lo 8KB) into LDS buffer pb, register-free
    auto stageW = [&](int c, int pb) {
        const char* hsrc = (const char*)wh + (size_t)c * 8192;
        const char* lsrc = (const char*)wl + (size_t)c * 8192;
        char* dst = smem + pb * 16384;
        #pragma unroll
        for (int i = 0; i < 2; ++i) {
            const int o = wid * 2048 + i * 1024;
            gll16(hsrc + o + lane * 16, dst + o);
            gll16(lsrc + o + lane * 16, dst + 8192 + o);
        }
    };

    auto computeChunk = [&](int cn, int pb, bool doLoad) {
        const uint4* wb = reinterpret_cast<const uint4*>(smem + pb * 16384);
        #pragma unroll
        for (int s = 0; s < 2; ++s) {
            FragU bh[4], bl[4];
            #pragma unroll
            for (int ni = 0; ni < 4; ++ni) {
                bh[ni].u = wb[s*256 + ni*64 + lane];         // hi planes
                bl[ni].u = wb[512 + s*256 + ni*64 + lane];   // lo planes
            }
            FragU ah[2], al[2];
            cvt8(xr[0*4 + s*2], xr[0*4 + s*2 + 1], ah[0].u, al[0].u);
            cvt8(xr[1*4 + s*2], xr[1*4 + s*2 + 1], ah[1].u, al[1].u);
            if (s == 1 && doLoad) loadX(cn);   // xr consumed; refill async
            #pragma unroll
            for (int mi = 0; mi < 2; ++mi)
                #pragma unroll
                for (int ni = 0; ni < 4; ++ni) {
                    acc[mi][ni] = __builtin_amdgcn_mfma_f32_16x16x32_bf16(ah[mi].v, bh[ni].v, acc[mi][ni], 0, 0, 0);
                    acc[mi][ni] = __builtin_amdgcn_mfma_f32_16x16x32_bf16(ah[mi].v, bl[ni].v, acc[mi][ni], 0, 0, 0);
                    acc[mi][ni] = __builtin_amdgcn_mfma_f32_16x16x32_bf16(al[mi].v, bh[ni].v, acc[mi][ni], 0, 0, 0);
                }
        }
    };

    // ---- staggered chunk order (decorrelates cross-block column windows) ----
    const int bofs = blockIdx.x % NCHUNK;

    stageW(bofs, 0);
    loadX(bofs);
    __syncthreads();

    int cc = bofs;
    #pragma unroll 1
    for (int c = 0; c < NCHUNK; ++c) {
        int ccn = cc + 1; if (ccn == NCHUNK) ccn = 0;
        const bool more = (c + 1 < NCHUNK);
        if (more) stageW(ccn, (c + 1) & 1);
        computeChunk(ccn, c & 1, more);
        __syncthreads();
        cc = ccn;
    }

    // ---- C-write: logits + bias into f32 LDS (aliases W bufs) ----
    float* ls = reinterpret_cast<float*>(smem);
    #pragma unroll
    for (int mi = 0; mi < 2; ++mi)
        #pragma unroll
        for (int ni = 0; ni < 4; ++ni) {
            const float be = b[ni*16 + lrow];
            #pragma unroll
            for (int r = 0; r < 4; ++r) {
                const int tl = wid*32 + mi*16 + lk*4 + r;
                const int e  = ni*16 + lrow;
                ls[tl * LSTR + e] = acc[mi][ni][r] + be;
            }
        }
    __syncthreads();

    // ---- per-token top-8 + margin + softmax (1 thread : 1 token) ----
    if (tid < BM) {
        float* row = ls + tid * LSTR;
        unsigned long long selm = 0ULL;
        float mx = 0.f, l8 = 0.f, l9 = 0.f;
        for (int s = 0; s < TOPK + 1; ++s) {
            float best = -1e30f; int bi = 0;
            #pragma unroll
            for (int e = 0; e < NE; ++e) {
                const float v = row[e];
                if (!((selm >> e) & 1ULL) && v > best) { best = v; bi = e; }
            }
            if (s == 0) mx = best;
            if (s < TOPK) selm |= 1ULL << bi;
            if (s == TOPK - 1) l8 = best;
            if (s == TOPK)     l9 = best;
        }
        if (l8 - l9 < MARGIN) {
            // publish directly: device-scope atomic, order irrelevant
            const int slot = atomicAdd(flagbuf, 1);
            flagbuf[1 + slot] = bm + tid;
        }
        float tot = 0.f, s8 = 0.f;
        #pragma unroll
        for (int e = 0; e < NE; ++e) {
            const float p = __expf(row[e] - mx);
            tot += p;
            if ((selm >> e) & 1ULL) s8 += p;
            row[e] = p;
        }
        const float inv = 1.f / (s8 + 1e-9f * tot);
        #pragma unroll
        for (int e = 0; e < NE; ++e)
            row[e] = ((selm >> e) & 1ULL) ? row[e] * inv : 0.f;
    }
    __syncthreads();

    // ---- coalesced float4 store ----
    {
        const int tx = tid & 15, ty = tid >> 4;
        #pragma unroll
        for (int r = 0; r < 8; ++r) {
            const int m = ty + r * 16;
            float4 v;
            v.x = ls[m * LSTR + tx*4 + 0];
            v.y = ls[m * LSTR + tx*4 + 1];
            v.z = ls[m * LSTR + tx*4 + 2];
            v.w = ls[m * LSTR + tx*4 + 3];
            *reinterpret_cast<float4*>(out + (size_t)(bm + m) * NE + tx*4) = v;
        }
    }
}

// ---- exact f64 referee for margin-flagged tokens (reads original f32 W) ----
__global__ __launch_bounds__(256)
void gate_refine(const float* __restrict__ h,
                 const float* __restrict__ u,
                 const float* __restrict__ W,
                 const float* __restrict__ b,
                 const int* __restrict__ flagbuf,
                 float* __restrict__ out)
{
    __shared__ double dscr[576];
    const int nf = flagbuf[0];
    for (int f = blockIdx.x; f < nf; f += gridDim.x) {
        const int tok  = flagbuf[1 + f];
        const int tid  = threadIdx.x;
        const int e    = tid & 63;
        const int part = tid >> 6;
        const int ka = part * 544, kb2 = ka + 544;
        double s = 0.0;
        #pragma unroll 4
        for (int k = ka; k < kb2; ++k) {
            const float xv = (k < EMB) ? h[(size_t)tok * EMB + k]
                                       : u[(size_t)tok * UDIM + (k - EMB)];
            s = fma((double)xv, (double)W[(size_t)e * KDIM + k], s);
        }
        dscr[part * 64 + e] = s;
        __syncthreads();
        if (tid < NE) {
            const double l = dscr[tid] + dscr[64 + tid] + dscr[128 + tid] +
                             dscr[192 + tid] + (double)b[tid];
            dscr[512 + tid] = l;
        }
        __syncthreads();
        if (tid == 0) {
            double* dl = dscr + 512;
            double mx = dl[0];
            #pragma unroll
            for (int e2 = 1; e2 < NE; ++e2) mx = fmax(mx, dl[e2]);
            double tot = 0.0;
            #pragma unroll
            for (int e2 = 0; e2 < NE; ++e2) {
                const double p = exp(dl[e2] - mx);
                dl[e2] = p;
                tot += p;
            }
            double s8 = 0.0;
            for (int ss = 0; ss < TOPK; ++ss) {
                double best = -1.0; int bi = 0;
                for (int e2 = 0; e2 < NE; ++e2) {
                    const double p = dl[e2];
                    if (p > best) { best = p; bi = e2; }
                }
                s8 += best;
                dl[bi] = -best;
            }
            const double inv = 1.0 / (s8 + 1e-9 * tot);
            for (int e2 = 0; e2 < NE; ++e2) {
                const double p = dl[e2];
                out[(size_t)tok * NE + e2] = (float)((p < 0.0) ? (-p) * inv : 0.0);
            }
        }
        __syncthreads();
    }
}

extern "C" void kernel_launch(void* const* d_in, const int* in_sizes, int n_in,
                              void* d_out, int out_size, void* d_ws, size_t ws_size,
                              hipStream_t stream) {
    const float* h = (const float*)d_in[0];
    const float* u = (const float*)d_in[1];
    const float* W = (const float*)d_in[2];
    const float* b = (const float*)d_in[3];
    float* out = (float*)d_out;
    (void)in_sizes; (void)n_in; (void)out_size; (void)ws_size;

    unsigned short* wh = (unsigned short*)d_ws;
    unsigned short* wl = wh + WPLANE;
    int* flagbuf = (int*)(wl + WPLANE);

    hipLaunchKernelGGL(prep_w, dim3(NKSTEP), dim3(256), 0, stream, W, wh, wl, flagbuf);
    hipLaunchKernelGGL(gate_main, dim3(NTOK / BM), dim3(256), 0, stream,
                       h, u, wh, wl, b, flagbuf, out);
    hipLaunchKernelGGL(gate_refine, dim3(256), dim3(256), 0, stream,
                       h, u, W, b, flagbuf, out);
}